// Round 3
// baseline (422.658 us; speedup 1.0000x reference)
//
#include <hip/hip_runtime.h>
#include <math.h>

#define Bv 64
#define Jv 20000
#define BG 4      // b's per block
#define NBG 16    // 64/4
#define NJB 79    // ceil(20000/256)

// ---------------- fused per-(b,j) kernel ----------------
// Block = 256 j's x BG b's. Each thread computes per-j terms once (pre1 in
// registers), reuses across BG sequential b's. LN1 stats via closed form.
__global__ __launch_bounds__(256) void pe_fused(
    const float* __restrict__ x, const int* __restrict__ mask,
    const int* __restrict__ atse_idx, const float* __restrict__ fe,
    const float* __restrict__ ae,
    const float* __restrict__ hW1, const float* __restrict__ hb1,
    const float* __restrict__ hl1g, const float* __restrict__ hl1b,
    const float* __restrict__ hW2, const float* __restrict__ hb2,
    const float* __restrict__ hl2g, const float* __restrict__ hl2b,
    const float* __restrict__ gW1, const float* __restrict__ gb1,
    const float* __restrict__ gW2, const float* __restrict__ gb2,
    float* __restrict__ acc_g, float* __restrict__ se_g) {
  __shared__ __align__(16) float s_hW1[33 * 64];   // rows: [w0 | F-part]
  __shared__ __align__(16) float s_gW1b[16 * 24];  // ae rows of g_W1
  __shared__ __align__(16) float s_W2[64 * 32];
  __shared__ __align__(16) float s_gW1h[32 * 24];  // h rows of g_W1
  __shared__ __align__(16) float s_gW2[24 * 4];
  __shared__ __align__(16) float s_hb1[64], s_l1g[64], s_l1b[64];
  __shared__ __align__(16) float s_b2[32], s_l2g[32], s_l2b[32];
  __shared__ __align__(16) float s_gb1[24];
  __shared__ float s_gb2[4];
  __shared__ float s_e[256 * 5];   // stride 5 (2-way worst: free)
  __shared__ float s_h[256 * 17];  // stride 17 (2-way worst: free)
  __shared__ float s_part[256];
  __shared__ float s_parte[16];

  int tid = threadIdx.x;
  int bg = blockIdx.x;
  int jbase = blockIdx.y * 256;

  for (int i = tid; i < 33 * 64; i += 256) s_hW1[i] = hW1[i];
  for (int i = tid; i < 16 * 24; i += 256) s_gW1b[i] = gW1[32 * 24 + i];
  for (int i = tid; i < 64 * 32; i += 256) s_W2[i] = hW2[i];
  for (int i = tid; i < 32 * 24; i += 256) s_gW1h[i] = gW1[i];
  if (tid < 96) s_gW2[tid] = gW2[tid];
  if (tid < 64) { s_hb1[tid] = hb1[tid]; s_l1g[tid] = hl1g[tid]; s_l1b[tid] = hl1b[tid]; }
  if (tid < 32) { s_b2[tid] = hb2[tid]; s_l2g[tid] = hl2g[tid]; s_l2b[tid] = hl2b[tid]; }
  if (tid < 24) s_gb1[tid] = gb1[tid];
  if (tid < 4) s_gb2[tid] = gb2[tid];
  __syncthreads();

  int j = jbase + tid;
  bool jok = j < Jv;
  int jc = jok ? j : (Jv - 1);

  // ---- per-j pre-phase: pre1 (p4) in registers + LN1 closed-form sums ----
  float F[32];
  {
    const float4* fv = (const float4*)(fe + (size_t)jc * 32);
#pragma unroll
    for (int q = 0; q < 8; ++q) {
      float4 v = fv[q];
      F[q * 4] = v.x; F[q * 4 + 1] = v.y; F[q * 4 + 2] = v.z; F[q * 4 + 3] = v.w;
    }
  }
  float4 p4[16];
#pragma unroll
  for (int k4 = 0; k4 < 16; ++k4) p4[k4] = ((const float4*)s_hb1)[k4];
#pragma unroll 4
  for (int d = 0; d < 32; ++d) {
    float Fd = F[d];
    const float4* wr = (const float4*)(s_hW1 + (1 + d) * 64);
#pragma unroll
    for (int k4 = 0; k4 < 16; ++k4) {
      float4 w = wr[k4];
      p4[k4].x = fmaf(Fd, w.x, p4[k4].x);
      p4[k4].y = fmaf(Fd, w.y, p4[k4].y);
      p4[k4].z = fmaf(Fd, w.z, p4[k4].z);
      p4[k4].w = fmaf(Fd, w.w, p4[k4].w);
    }
  }
  float sp = 0.f, qp = 0.f, dwp = 0.f, Sw0 = 0.f, Qw0 = 0.f;
#pragma unroll
  for (int k4 = 0; k4 < 16; ++k4) {
    float4 a = p4[k4];
    float4 w0 = ((const float4*)s_hW1)[k4];
    sp += a.x + a.y + a.z + a.w;
    qp = fmaf(a.x, a.x, qp); qp = fmaf(a.y, a.y, qp);
    qp = fmaf(a.z, a.z, qp); qp = fmaf(a.w, a.w, qp);
    dwp = fmaf(a.x, w0.x, dwp); dwp = fmaf(a.y, w0.y, dwp);
    dwp = fmaf(a.z, w0.z, dwp); dwp = fmaf(a.w, w0.w, dwp);
    Sw0 += w0.x + w0.y + w0.z + w0.w;
    Qw0 = fmaf(w0.x, w0.x, Qw0); Qw0 = fmaf(w0.y, w0.y, Qw0);
    Qw0 = fmaf(w0.z, w0.z, Qw0); Qw0 = fmaf(w0.w, w0.w, Qw0);
  }

  // ---- per-j gate bias: ae part of g_W1 + g_b1 ----
  float4 ge4[6];
  {
    int ai = atse_idx[jc];
    const float4* av = (const float4*)(ae + (size_t)ai * 16);
    float A[16];
#pragma unroll
    for (int q = 0; q < 4; ++q) {
      float4 v = av[q];
      A[q * 4] = v.x; A[q * 4 + 1] = v.y; A[q * 4 + 2] = v.z; A[q * 4 + 3] = v.w;
    }
#pragma unroll
    for (int c4 = 0; c4 < 6; ++c4) ge4[c4] = ((const float4*)s_gb1)[c4];
#pragma unroll
    for (int a = 0; a < 16; ++a) {
      float Av = A[a];
      const float4* row = (const float4*)(s_gW1b + a * 24);
#pragma unroll
      for (int c4 = 0; c4 < 6; ++c4) {
        float4 w = row[c4];
        ge4[c4].x = fmaf(Av, w.x, ge4[c4].x);
        ge4[c4].y = fmaf(Av, w.y, ge4[c4].y);
        ge4[c4].z = fmaf(Av, w.z, ge4[c4].z);
        ge4[c4].w = fmaf(Av, w.w, ge4[c4].w);
      }
    }
  }

  // ---- loop over BG b's, reusing p4/ge4 ----
  for (int bb = 0; bb < BG; ++bb) {
    int brow = bg * BG + bb;
    float xv = 0.f;
    int mv = 0;
    if (jok) {
      xv = x[(size_t)brow * Jv + j];      // coalesced
      mv = mask[(size_t)brow * Jv + j];   // coalesced
    }
    float mu1 = fmaf(xv, Sw0, sp) * (1.0f / 64.0f);
    float Et2 = (xv * xv * Qw0 + 2.0f * xv * dwp + qp) * (1.0f / 64.0f);
    float rs1 = rsqrtf(fmaxf(Et2 - mu1 * mu1, 0.0f) + 1e-5f);

    float h2[32];
#pragma unroll
    for (int q = 0; q < 8; ++q) {
      float4 bbv = ((const float4*)s_b2)[q];
      h2[4 * q] = bbv.x; h2[4 * q + 1] = bbv.y;
      h2[4 * q + 2] = bbv.z; h2[4 * q + 3] = bbv.w;
    }
#pragma unroll 4
    for (int k4 = 0; k4 < 16; ++k4) {
      float4 pp = p4[k4];
      float4 w04 = ((const float4*)s_hW1)[k4];
      float4 g4 = ((const float4*)s_l1g)[k4];
      float4 b4 = ((const float4*)s_l1b)[k4];
      float av[4];
      av[0] = fmaxf(fmaf((fmaf(xv, w04.x, pp.x) - mu1) * rs1, g4.x, b4.x), 0.f);
      av[1] = fmaxf(fmaf((fmaf(xv, w04.y, pp.y) - mu1) * rs1, g4.y, b4.y), 0.f);
      av[2] = fmaxf(fmaf((fmaf(xv, w04.z, pp.z) - mu1) * rs1, g4.z, b4.z), 0.f);
      av[3] = fmaxf(fmaf((fmaf(xv, w04.w, pp.w) - mu1) * rs1, g4.w, b4.w), 0.f);
#pragma unroll
      for (int u = 0; u < 4; ++u) {
        float a = av[u];
        const float4* row = (const float4*)(s_W2 + (k4 * 4 + u) * 32);
#pragma unroll
        for (int q = 0; q < 8; ++q) {
          float4 w = row[q];
          h2[4 * q]     = fmaf(a, w.x, h2[4 * q]);
          h2[4 * q + 1] = fmaf(a, w.y, h2[4 * q + 1]);
          h2[4 * q + 2] = fmaf(a, w.z, h2[4 * q + 2]);
          h2[4 * q + 3] = fmaf(a, w.w, h2[4 * q + 3]);
        }
      }
    }
    // LN2 + relu in place
    {
      float s = 0.f;
#pragma unroll
      for (int d = 0; d < 32; ++d) s += h2[d];
      float mu2 = s * (1.0f / 32.0f);
      float vv = 0.f;
#pragma unroll
      for (int d = 0; d < 32; ++d) { float dd = h2[d] - mu2; vv = fmaf(dd, dd, vv); }
      float rs2 = rsqrtf(vv * (1.0f / 32.0f) + 1e-5f);
#pragma unroll
      for (int d = 0; d < 32; ++d)
        h2[d] = fmaxf(fmaf((h2[d] - mu2) * rs2, s_l2g[d], s_l2b[d]), 0.f);
    }
    // gate
    float e0, e1, e2, e3;
    {
      float g1[24];
#pragma unroll
      for (int c4 = 0; c4 < 6; ++c4) {
        g1[4 * c4] = ge4[c4].x; g1[4 * c4 + 1] = ge4[c4].y;
        g1[4 * c4 + 2] = ge4[c4].z; g1[4 * c4 + 3] = ge4[c4].w;
      }
#pragma unroll 8
      for (int i = 0; i < 32; ++i) {
        float hv = h2[i];
        const float4* row = (const float4*)(s_gW1h + i * 24);
#pragma unroll
        for (int c4 = 0; c4 < 6; ++c4) {
          float4 w = row[c4];
          g1[4 * c4]     = fmaf(hv, w.x, g1[4 * c4]);
          g1[4 * c4 + 1] = fmaf(hv, w.y, g1[4 * c4 + 1]);
          g1[4 * c4 + 2] = fmaf(hv, w.z, g1[4 * c4 + 2]);
          g1[4 * c4 + 3] = fmaf(hv, w.w, g1[4 * c4 + 3]);
        }
      }
      float r0 = s_gb2[0], r1 = s_gb2[1], r2 = s_gb2[2], r3 = s_gb2[3];
#pragma unroll
      for (int c = 0; c < 24; ++c) {
        float gv = fmaxf(g1[c], 0.0f);
        float4 w = ((const float4*)s_gW2)[c];
        r0 = fmaf(gv, w.x, r0);
        r1 = fmaf(gv, w.y, r1);
        r2 = fmaf(gv, w.z, r2);
        r3 = fmaf(gv, w.w, r3);
      }
      // clip; exp shifted by clip ceiling (10): masked lanes contribute 0
      r0 = fminf(fmaxf(r0, -10.f), 10.f);
      r1 = fminf(fmaxf(r1, -10.f), 10.f);
      r2 = fminf(fmaxf(r2, -10.f), 10.f);
      r3 = fminf(fmaxf(r3, -10.f), 10.f);
      bool act = jok && (mv != 0);
      e0 = act ? __expf(r0 - 10.f) : 0.f;
      e1 = act ? __expf(r1 - 10.f) : 0.f;
      e2 = act ? __expf(r2 - 10.f) : 0.f;
      e3 = act ? __expf(r3 - 10.f) : 0.f;
    }

    // ---- block reduce: acc[w][d] += sum_t e_w * h_d ; se[w] += sum_t e_w ----
    s_e[tid * 5 + 0] = e0;
    s_e[tid * 5 + 1] = e1;
    s_e[tid * 5 + 2] = e2;
    s_e[tid * 5 + 3] = e3;
#pragma unroll
    for (int dd = 0; dd < 16; ++dd) s_h[tid * 17 + dd] = h2[dd];
    __syncthreads();
    int seg = tid >> 6, p = tid & 63, w = p >> 4, dd0 = p & 15;
    {
      float a = 0.f, aes = 0.f;
      int i0 = seg * 64;
#pragma unroll 8
      for (int i = i0; i < i0 + 64; ++i) {
        float ev = s_e[i * 5 + w];
        a = fmaf(ev, s_h[i * 17 + dd0], a);
        aes += ev;
      }
      s_part[p * 4 + seg] = a;
      if (dd0 == 0) s_parte[w * 4 + seg] = aes;
    }
    __syncthreads();
    if (tid < 64) {
      float tot = s_part[tid * 4 + 0] + s_part[tid * 4 + 1] +
                  s_part[tid * 4 + 2] + s_part[tid * 4 + 3];
      int ww = tid >> 4, d = tid & 15;
      atomicAdd(&acc_g[brow * 128 + ww * 32 + d], tot);
    }
    if (tid < 4) {
      float tot = s_parte[tid * 4 + 0] + s_parte[tid * 4 + 1] +
                  s_parte[tid * 4 + 2] + s_parte[tid * 4 + 3];
      atomicAdd(&se_g[brow * 4 + tid], tot);
    }
    // chunk 1: d in [16,32)
#pragma unroll
    for (int dd = 0; dd < 16; ++dd) s_h[tid * 17 + dd] = h2[16 + dd];
    __syncthreads();
    {
      float a = 0.f;
      int i0 = seg * 64;
#pragma unroll 8
      for (int i = i0; i < i0 + 64; ++i)
        a = fmaf(s_e[i * 5 + w], s_h[i * 17 + dd0], a);
      s_part[p * 4 + seg] = a;
    }
    __syncthreads();
    if (tid < 64) {
      float tot = s_part[tid * 4 + 0] + s_part[tid * 4 + 1] +
                  s_part[tid * 4 + 2] + s_part[tid * 4 + 3];
      int ww = tid >> 4, d = tid & 15;
      atomicAdd(&acc_g[brow * 128 + ww * 32 + 16 + d], tot);
    }
    __syncthreads();  // protect s_e/s_h/s_part before next bb overwrites
  }
}

// ---------------- per-b tail: normalize, c-layer, encoder MLP ----------------
__global__ __launch_bounds__(64) void pe_tail(
    const float* __restrict__ acc_g, const float* __restrict__ se_g,
    const float* __restrict__ cW, const float* __restrict__ cb,
    const float* __restrict__ clng, const float* __restrict__ clnb,
    const float* __restrict__ eW1, const float* __restrict__ eb1,
    const float* __restrict__ eW2, const float* __restrict__ eb2,
    float* __restrict__ out) {
  int b = blockIdx.x;
  int lane = threadIdx.x;  // 64 threads = 1 wave
  __shared__ float s_hs[128], s_comb[32], s_e1[128];

  float se0 = se_g[b * 4 + 0];
  bool empty = !(se0 > 0.0f);
  float inv[4];
#pragma unroll
  for (int w = 0; w < 4; ++w) {
    float sw = se_g[b * 4 + w];
    inv[w] = empty ? 0.0f : 1.0f / sw;
  }
  s_hs[lane] = acc_g[b * 128 + lane] * inv[lane >> 5];
  s_hs[lane + 64] = acc_g[b * 128 + lane + 64] * inv[(lane + 64) >> 5];
  __syncthreads();

  if (lane < 32) {
    float cp = cb[lane];
#pragma unroll 8
    for (int i = 0; i < 128; ++i) cp = fmaf(s_hs[i], cW[i * 32 + lane], cp);
    float ssum = cp;
#pragma unroll
    for (int off = 16; off > 0; off >>= 1) ssum += __shfl_xor(ssum, off, 32);
    float mu = ssum * (1.0f / 32.0f);
    float dd = cp - mu;
    float sq = dd * dd;
#pragma unroll
    for (int off = 16; off > 0; off >>= 1) sq += __shfl_xor(sq, off, 32);
    float rs = rsqrtf(sq * (1.0f / 32.0f) + 1e-5f);
    float comb = fmaxf(fmaf(dd * rs, clng[lane], clnb[lane]), 0.0f);
    if (empty) comb = 0.0f;
    s_comb[lane] = comb;
  }
  __syncthreads();

  float v0 = eb1[lane], v1 = eb1[lane + 64];
#pragma unroll
  for (int i = 0; i < 32; ++i) {
    float c = s_comb[i];
    v0 = fmaf(c, eW1[i * 128 + lane], v0);
    v1 = fmaf(c, eW1[i * 128 + lane + 64], v1);
  }
  float ssum = v0 + v1;
#pragma unroll
  for (int off = 32; off > 0; off >>= 1) ssum += __shfl_xor(ssum, off, 64);
  float mu = ssum * (1.0f / 128.0f);
  float d0 = v0 - mu, d1 = v1 - mu;
  float sq = fmaf(d0, d0, d1 * d1);
#pragma unroll
  for (int off = 32; off > 0; off >>= 1) sq += __shfl_xor(sq, off, 64);
  float rs = rsqrtf(sq * (1.0f / 128.0f) + 1e-5f);
  s_e1[lane] = fmaxf(d0 * rs, 0.0f);
  s_e1[lane + 64] = fmaxf(d1 * rs, 0.0f);
  __syncthreads();

  float v = eb2[lane];
#pragma unroll 8
  for (int i = 0; i < 128; ++i) v = fmaf(s_e1[i], eW2[i * 64 + lane], v);
  ssum = v;
#pragma unroll
  for (int off = 32; off > 0; off >>= 1) ssum += __shfl_xor(ssum, off, 64);
  mu = ssum * (1.0f / 64.0f);
  float dv = v - mu;
  sq = dv * dv;
#pragma unroll
  for (int off = 32; off > 0; off >>= 1) sq += __shfl_xor(sq, off, 64);
  rs = rsqrtf(sq * (1.0f / 64.0f) + 1e-5f);
  float o = fmaxf(dv * rs, 0.0f);
  if (lane < 32)
    out[b * 32 + lane] = o;                       // mu
  else
    out[Bv * 32 + b * 32 + (lane - 32)] = o;      // logvar
}

extern "C" void kernel_launch(void* const* d_in, const int* in_sizes, int n_in,
                              void* d_out, int out_size, void* d_ws, size_t ws_size,
                              hipStream_t stream) {
  const float* x    = (const float*)d_in[0];
  const int* mask   = (const int*)d_in[1];
  const int* atse   = (const int*)d_in[2];
  const float* fe   = (const float*)d_in[3];
  const float* ae   = (const float*)d_in[4];
  const float* hW1  = (const float*)d_in[5];
  const float* hb1  = (const float*)d_in[6];
  const float* hl1g = (const float*)d_in[7];
  const float* hl1b = (const float*)d_in[8];
  const float* hW2  = (const float*)d_in[9];
  const float* hb2  = (const float*)d_in[10];
  const float* hl2g = (const float*)d_in[11];
  const float* hl2b = (const float*)d_in[12];
  const float* gW1  = (const float*)d_in[13];
  const float* gb1  = (const float*)d_in[14];
  const float* gW2  = (const float*)d_in[15];
  const float* gb2  = (const float*)d_in[16];
  const float* cW   = (const float*)d_in[17];
  const float* cb   = (const float*)d_in[18];
  const float* clng = (const float*)d_in[19];
  const float* clnb = (const float*)d_in[20];
  const float* eW1  = (const float*)d_in[21];
  const float* eb1  = (const float*)d_in[22];
  const float* eW2  = (const float*)d_in[23];
  const float* eb2  = (const float*)d_in[24];
  float* out = (float*)d_out;

  float* ws = (float*)d_ws;
  float* accg = ws;                 // B*128 floats
  float* seg  = accg + Bv * 128;    // B*4 floats

  hipMemsetAsync(accg, 0, (Bv * 128 + Bv * 4) * sizeof(float), stream);

  pe_fused<<<dim3(NBG, NJB), dim3(256), 0, stream>>>(
      x, mask, atse, fe, ae, hW1, hb1, hl1g, hl1b, hW2, hb2, hl2g, hl2b,
      gW1, gb1, gW2, gb2, accg, seg);
  pe_tail<<<dim3(Bv), dim3(64), 0, stream>>>(
      accg, seg, cW, cb, clng, clnb, eW1, eb1, eW2, eb2, out);
}

// Round 4
// 314.051 us; speedup vs baseline: 1.3458x; 1.3458x over previous
//
#include <hip/hip_runtime.h>
#include <math.h>

#define Bv 64
#define Jv 20000
#define TJ 32
#define TB 32
#define NJT 625   // 20000/32
#define NBT 2     // 64/32

// Block = 32 j x 32 b. Per-j state (pre1, gate bias, LN1 stats) computed once
// into LDS, reused by all 32 b's. 4 rounds of 256 pairs each; per-round LDS
// reduce into per-thread register accumulators; one coalesced atomic pass/block.
__global__ __launch_bounds__(256) void pe_fused(
    const float* __restrict__ x, const int* __restrict__ mask,
    const int* __restrict__ atse_idx, const float* __restrict__ fe,
    const float* __restrict__ ae,
    const float* __restrict__ hW1, const float* __restrict__ hb1,
    const float* __restrict__ hl1g, const float* __restrict__ hl1b,
    const float* __restrict__ hW2, const float* __restrict__ hb2,
    const float* __restrict__ hl2g, const float* __restrict__ hl2b,
    const float* __restrict__ gW1, const float* __restrict__ gb1,
    const float* __restrict__ gW2, const float* __restrict__ gb2,
    float* __restrict__ acc_g, float* __restrict__ se_g) {
  __shared__ __align__(16) float s_pre1[TJ * 68];   // stride 68: f4-aligned
  __shared__ __align__(16) float s_ex[TJ * 4];      // sp, qp, dwp per j
  __shared__ __align__(16) float s_gb[TJ * 28];     // stride 28: f4-aligned
  __shared__ __align__(16) float s_W2[64 * 32];
  __shared__ __align__(16) float s_gW1h[32 * 24];
  __shared__ __align__(16) float s_gW2[96];
  __shared__ __align__(16) float s_w0[64], s_l1g[64], s_l1b[64], s_hb1[64];
  __shared__ __align__(16) float s_b2[32], s_l2g[32], s_l2b[32];
  __shared__ __align__(16) float s_gb1[24];
  __shared__ float s_gb2[4], s_scal[2];
  // overlay: pre-phase {fe[32*33], hW1f[2048], ae[32*20], gW1b[384]} = 4128
  //          rounds    {s_e[256*5]=1280, s_h[256*17]=4352}           = 5632
  //          final     {s_red[32*132]=4224}
  __shared__ __align__(16) float s_ovl[5632];

  int tid = threadIdx.x;
  int btile = blockIdx.x;   // 0..1
  int jtile = blockIdx.y;   // 0..624

  float* s_fe   = s_ovl;            // [32][33]
  float* s_hW1f = s_ovl + 1056;     // [32][64] rows 1..32 of hW1
  float* s_ae   = s_ovl + 3104;     // [32][20]
  float* s_gW1b = s_ovl + 3744;     // [16][24]
  float* s_e    = s_ovl;            // [256][5]
  float* s_h    = s_ovl + 1280;     // [256][17]
  float* s_red  = s_ovl;            // [32][132]

  // ---------------- stage ----------------
  for (int i = tid; i < 2048; i += 256) s_W2[i] = hW2[i];
  for (int i = tid; i < 768; i += 256) s_gW1h[i] = gW1[i];
  for (int i = tid; i < 1024; i += 256)
    s_fe[(i >> 5) * 33 + (i & 31)] = fe[(size_t)jtile * 1024 + i];
  for (int i = tid; i < 2048; i += 256) s_hW1f[i] = hW1[64 + i];
  for (int i = tid; i < 384; i += 256) s_gW1b[i] = gW1[768 + i];
  if (tid < 96) s_gW2[tid] = gW2[tid];
  if (tid < 64) {
    s_w0[tid] = hW1[tid]; s_l1g[tid] = hl1g[tid];
    s_l1b[tid] = hl1b[tid]; s_hb1[tid] = hb1[tid];
  }
  if (tid < 32) { s_b2[tid] = hb2[tid]; s_l2g[tid] = hl2g[tid]; s_l2b[tid] = hl2b[tid]; }
  if (tid < 24) s_gb1[tid] = gb1[tid];
  if (tid < 4) s_gb2[tid] = gb2[tid];
  if (tid < 32) {
    int ai = atse_idx[jtile * 32 + tid];
    const float4* av = (const float4*)(ae + (size_t)ai * 16);
#pragma unroll
    for (int q = 0; q < 4; ++q) *(float4*)(s_ae + tid * 20 + q * 4) = av[q];
  }
  __syncthreads();

  // ---------------- per-j pre-compute ----------------
  {
    int jp = tid >> 3, ks = tid & 7;  // 8 threads per j; 8 k's per thread
    float a8[8];
#pragma unroll
    for (int kk = 0; kk < 8; ++kk) a8[kk] = s_hb1[ks * 8 + kk];
#pragma unroll 4
    for (int d = 0; d < 32; ++d) {
      float Fd = s_fe[jp * 33 + d];
      const float* wr = s_hW1f + d * 64 + ks * 8;
#pragma unroll
      for (int kk = 0; kk < 8; ++kk) a8[kk] = fmaf(Fd, wr[kk], a8[kk]);
    }
#pragma unroll
    for (int kk = 0; kk < 8; ++kk) s_pre1[jp * 68 + ks * 8 + kk] = a8[kk];

    // gate bias: c = (tid&7)*3 + {0,1,2}
    int c0 = ks * 3;
    float g3[3] = {s_gb1[c0], s_gb1[c0 + 1], s_gb1[c0 + 2]};
#pragma unroll 4
    for (int a = 0; a < 16; ++a) {
      float Av = s_ae[jp * 20 + a];
      const float* gr = s_gW1b + a * 24 + c0;
      g3[0] = fmaf(Av, gr[0], g3[0]);
      g3[1] = fmaf(Av, gr[1], g3[1]);
      g3[2] = fmaf(Av, gr[2], g3[2]);
    }
    s_gb[jp * 28 + c0] = g3[0];
    s_gb[jp * 28 + c0 + 1] = g3[1];
    s_gb[jp * 28 + c0 + 2] = g3[2];
  }
  __syncthreads();

  // ---------------- LN1 closed-form stats ----------------
  if (tid < 32) {
    float sp = 0.f, qp = 0.f, dwp = 0.f;
#pragma unroll 8
    for (int k = 0; k < 64; ++k) {
      float p = s_pre1[tid * 68 + k];
      float w = s_w0[k];
      sp += p;
      qp = fmaf(p, p, qp);
      dwp = fmaf(p, w, dwp);
    }
    ((float4*)s_ex)[tid] = make_float4(sp, qp, dwp, 0.f);
  } else if (tid == 32) {
    float sw = 0.f, qw = 0.f;
    for (int k = 0; k < 64; ++k) {
      float w = s_w0[k];
      sw += w;
      qw = fmaf(w, w, qw);
    }
    s_scal[0] = sw;
    s_scal[1] = qw;
  }
  __syncthreads();

  // ---------------- 4 rounds of 256 pairs ----------------
  int cb = tid & 31, jg = tid >> 5;          // compute mapping
  int b = btile * 32 + cb;
  int rb = tid & 31, rw = (tid >> 5) & 3, rd8 = tid >> 7;  // reduce mapping
  float accA[8], accB[8];
#pragma unroll
  for (int i = 0; i < 8; ++i) { accA[i] = 0.f; accB[i] = 0.f; }
  float se_acc = 0.f;

  // all 4 rounds' x/mask in one vector load (jl = jg*4 + jj consecutive)
  const float4 xv4 = *(const float4*)(x + (size_t)b * Jv + jtile * 32 + jg * 4);
  const int4 mv4 = *(const int4*)(mask + (size_t)b * Jv + jtile * 32 + jg * 4);
  float xarr[4] = {xv4.x, xv4.y, xv4.z, xv4.w};
  int marr[4] = {mv4.x, mv4.y, mv4.z, mv4.w};

  for (int jj = 0; jj < 4; ++jj) {
    int jl = jg * 4 + jj;
    float xv = xarr[jj];
    float4 ex = ((const float4*)s_ex)[jl];
    float mu1 = fmaf(xv, s_scal[0], ex.x) * 0.015625f;
    float Et2 = fmaf(xv * xv, s_scal[1], fmaf(2.0f * xv, ex.z, ex.y)) * 0.015625f;
    float rs1 = rsqrtf(fmaxf(Et2 - mu1 * mu1, 0.f) + 1e-5f);
    float nm1 = -mu1 * rs1;

    float h2[32];
#pragma unroll
    for (int q = 0; q < 8; ++q) {
      float4 bb4 = ((const float4*)s_b2)[q];
      h2[4 * q] = bb4.x; h2[4 * q + 1] = bb4.y;
      h2[4 * q + 2] = bb4.z; h2[4 * q + 3] = bb4.w;
    }
    const float4* pr4 = (const float4*)(s_pre1 + jl * 68);
#pragma unroll 4
    for (int k4 = 0; k4 < 16; ++k4) {
      float4 p = pr4[k4];
      float4 w0 = ((const float4*)s_w0)[k4];
      float4 g4 = ((const float4*)s_l1g)[k4];
      float4 b4 = ((const float4*)s_l1b)[k4];
      float av[4];
      av[0] = fmaxf(fmaf(fmaf(fmaf(xv, w0.x, p.x), rs1, nm1), g4.x, b4.x), 0.f);
      av[1] = fmaxf(fmaf(fmaf(fmaf(xv, w0.y, p.y), rs1, nm1), g4.y, b4.y), 0.f);
      av[2] = fmaxf(fmaf(fmaf(fmaf(xv, w0.z, p.z), rs1, nm1), g4.z, b4.z), 0.f);
      av[3] = fmaxf(fmaf(fmaf(fmaf(xv, w0.w, p.w), rs1, nm1), g4.w, b4.w), 0.f);
#pragma unroll
      for (int u = 0; u < 4; ++u) {
        float a = av[u];
        const float4* row = (const float4*)(s_W2 + (k4 * 4 + u) * 32);
#pragma unroll
        for (int q = 0; q < 8; ++q) {
          float4 w = row[q];
          h2[4 * q]     = fmaf(a, w.x, h2[4 * q]);
          h2[4 * q + 1] = fmaf(a, w.y, h2[4 * q + 1]);
          h2[4 * q + 2] = fmaf(a, w.z, h2[4 * q + 2]);
          h2[4 * q + 3] = fmaf(a, w.w, h2[4 * q + 3]);
        }
      }
    }
    // LN2 + relu
    {
      float s = 0.f;
#pragma unroll
      for (int d = 0; d < 32; ++d) s += h2[d];
      float mu2 = s * 0.03125f;
      float vv = 0.f;
#pragma unroll
      for (int d = 0; d < 32; ++d) { float dd = h2[d] - mu2; vv = fmaf(dd, dd, vv); }
      float rs2 = rsqrtf(vv * 0.03125f + 1e-5f);
#pragma unroll
      for (int d = 0; d < 32; ++d)
        h2[d] = fmaxf(fmaf((h2[d] - mu2) * rs2, s_l2g[d], s_l2b[d]), 0.f);
    }
    // gate
    float e0, e1, e2, e3;
    {
      float g1[24];
      const float4* gbv = (const float4*)(s_gb + jl * 28);
#pragma unroll
      for (int c4 = 0; c4 < 6; ++c4) {
        float4 v = gbv[c4];
        g1[4 * c4] = v.x; g1[4 * c4 + 1] = v.y;
        g1[4 * c4 + 2] = v.z; g1[4 * c4 + 3] = v.w;
      }
#pragma unroll 8
      for (int i = 0; i < 32; ++i) {
        float hv = h2[i];
        const float4* row = (const float4*)(s_gW1h + i * 24);
#pragma unroll
        for (int c4 = 0; c4 < 6; ++c4) {
          float4 w = row[c4];
          g1[4 * c4]     = fmaf(hv, w.x, g1[4 * c4]);
          g1[4 * c4 + 1] = fmaf(hv, w.y, g1[4 * c4 + 1]);
          g1[4 * c4 + 2] = fmaf(hv, w.z, g1[4 * c4 + 2]);
          g1[4 * c4 + 3] = fmaf(hv, w.w, g1[4 * c4 + 3]);
        }
      }
      float r0 = s_gb2[0], r1 = s_gb2[1], r2 = s_gb2[2], r3 = s_gb2[3];
#pragma unroll
      for (int c = 0; c < 24; ++c) {
        float gv = fmaxf(g1[c], 0.0f);
        float4 w = ((const float4*)s_gW2)[c];
        r0 = fmaf(gv, w.x, r0);
        r1 = fmaf(gv, w.y, r1);
        r2 = fmaf(gv, w.z, r2);
        r3 = fmaf(gv, w.w, r3);
      }
      r0 = fminf(fmaxf(r0, -10.f), 10.f);
      r1 = fminf(fmaxf(r1, -10.f), 10.f);
      r2 = fminf(fmaxf(r2, -10.f), 10.f);
      r3 = fminf(fmaxf(r3, -10.f), 10.f);
      bool act = (marr[jj] != 0);
      e0 = act ? __expf(r0 - 10.f) : 0.f;
      e1 = act ? __expf(r1 - 10.f) : 0.f;
      e2 = act ? __expf(r2 - 10.f) : 0.f;
      e3 = act ? __expf(r3 - 10.f) : 0.f;
    }

    // ---- round reduce: chunk 0 (d 0..15) ----
    s_e[tid * 5 + 0] = e0;
    s_e[tid * 5 + 1] = e1;
    s_e[tid * 5 + 2] = e2;
    s_e[tid * 5 + 3] = e3;
#pragma unroll
    for (int dd = 0; dd < 16; ++dd) s_h[tid * 17 + dd] = h2[dd];
    __syncthreads();
    float ev[8];
#pragma unroll
    for (int g = 0; g < 8; ++g) ev[g] = s_e[(g * 32 + rb) * 5 + rw];
    if (rd8 == 0) {
#pragma unroll
      for (int g = 0; g < 8; ++g) se_acc += ev[g];
    }
#pragma unroll
    for (int g = 0; g < 8; ++g) {
      const float* hp = s_h + (g * 32 + rb) * 17 + rd8 * 8;
#pragma unroll
      for (int dd = 0; dd < 8; ++dd) accA[dd] = fmaf(ev[g], hp[dd], accA[dd]);
    }
    __syncthreads();
    // ---- chunk 1 (d 16..31) ----
#pragma unroll
    for (int dd = 0; dd < 16; ++dd) s_h[tid * 17 + dd] = h2[16 + dd];
    __syncthreads();
#pragma unroll
    for (int g = 0; g < 8; ++g) {
      const float* hp = s_h + (g * 32 + rb) * 17 + rd8 * 8;
#pragma unroll
      for (int dd = 0; dd < 8; ++dd) accB[dd] = fmaf(ev[g], hp[dd], accB[dd]);
    }
    __syncthreads();
  }

  // ---------------- block epilogue: coalesced atomics ----------------
#pragma unroll
  for (int dd = 0; dd < 8; ++dd) {
    s_red[rb * 132 + rw * 32 + rd8 * 8 + dd] = accA[dd];
    s_red[rb * 132 + rw * 32 + 16 + rd8 * 8 + dd] = accB[dd];
  }
  __syncthreads();
  for (int i = tid; i < 4096; i += 256) {
    int bb = i >> 7, o = i & 127;
    atomicAdd(&acc_g[(size_t)(btile * 32 + bb) * 128 + o], s_red[bb * 132 + o]);
  }
  if (rd8 == 0) atomicAdd(&se_g[(btile * 32 + rb) * 4 + rw], se_acc);
}

// ---------------- per-b tail: normalize, c-layer, encoder MLP ----------------
__global__ __launch_bounds__(64) void pe_tail(
    const float* __restrict__ acc_g, const float* __restrict__ se_g,
    const float* __restrict__ cW, const float* __restrict__ cb,
    const float* __restrict__ clng, const float* __restrict__ clnb,
    const float* __restrict__ eW1, const float* __restrict__ eb1,
    const float* __restrict__ eW2, const float* __restrict__ eb2,
    float* __restrict__ out) {
  int b = blockIdx.x;
  int lane = threadIdx.x;  // 64 threads = 1 wave
  __shared__ float s_hs[128], s_comb[32], s_e1[128];

  float se0 = se_g[b * 4 + 0];
  bool empty = !(se0 > 0.0f);
  float inv[4];
#pragma unroll
  for (int w = 0; w < 4; ++w) {
    float sw = se_g[b * 4 + w];
    inv[w] = empty ? 0.0f : 1.0f / sw;
  }
  s_hs[lane] = acc_g[b * 128 + lane] * inv[lane >> 5];
  s_hs[lane + 64] = acc_g[b * 128 + lane + 64] * inv[(lane + 64) >> 5];
  __syncthreads();

  if (lane < 32) {
    float cp = cb[lane];
#pragma unroll 8
    for (int i = 0; i < 128; ++i) cp = fmaf(s_hs[i], cW[i * 32 + lane], cp);
    float ssum = cp;
#pragma unroll
    for (int off = 16; off > 0; off >>= 1) ssum += __shfl_xor(ssum, off, 32);
    float mu = ssum * (1.0f / 32.0f);
    float dd = cp - mu;
    float sq = dd * dd;
#pragma unroll
    for (int off = 16; off > 0; off >>= 1) sq += __shfl_xor(sq, off, 32);
    float rs = rsqrtf(sq * (1.0f / 32.0f) + 1e-5f);
    float comb = fmaxf(fmaf(dd * rs, clng[lane], clnb[lane]), 0.0f);
    if (empty) comb = 0.0f;
    s_comb[lane] = comb;
  }
  __syncthreads();

  float v0 = eb1[lane], v1 = eb1[lane + 64];
#pragma unroll
  for (int i = 0; i < 32; ++i) {
    float c = s_comb[i];
    v0 = fmaf(c, eW1[i * 128 + lane], v0);
    v1 = fmaf(c, eW1[i * 128 + lane + 64], v1);
  }
  float ssum = v0 + v1;
#pragma unroll
  for (int off = 32; off > 0; off >>= 1) ssum += __shfl_xor(ssum, off, 64);
  float mu = ssum * (1.0f / 128.0f);
  float d0 = v0 - mu, d1 = v1 - mu;
  float sq = fmaf(d0, d0, d1 * d1);
#pragma unroll
  for (int off = 32; off > 0; off >>= 1) sq += __shfl_xor(sq, off, 64);
  float rs = rsqrtf(sq * (1.0f / 128.0f) + 1e-5f);
  s_e1[lane] = fmaxf(d0 * rs, 0.0f);
  s_e1[lane + 64] = fmaxf(d1 * rs, 0.0f);
  __syncthreads();

  float v = eb2[lane];
#pragma unroll 8
  for (int i = 0; i < 128; ++i) v = fmaf(s_e1[i], eW2[i * 64 + lane], v);
  ssum = v;
#pragma unroll
  for (int off = 32; off > 0; off >>= 1) ssum += __shfl_xor(ssum, off, 64);
  mu = ssum * (1.0f / 64.0f);
  float dv = v - mu;
  sq = dv * dv;
#pragma unroll
  for (int off = 32; off > 0; off >>= 1) sq += __shfl_xor(sq, off, 64);
  rs = rsqrtf(sq * (1.0f / 64.0f) + 1e-5f);
  float o = fmaxf(dv * rs, 0.0f);
  if (lane < 32)
    out[b * 32 + lane] = o;                       // mu
  else
    out[Bv * 32 + b * 32 + (lane - 32)] = o;      // logvar
}

extern "C" void kernel_launch(void* const* d_in, const int* in_sizes, int n_in,
                              void* d_out, int out_size, void* d_ws, size_t ws_size,
                              hipStream_t stream) {
  const float* x    = (const float*)d_in[0];
  const int* mask   = (const int*)d_in[1];
  const int* atse   = (const int*)d_in[2];
  const float* fe   = (const float*)d_in[3];
  const float* ae   = (const float*)d_in[4];
  const float* hW1  = (const float*)d_in[5];
  const float* hb1  = (const float*)d_in[6];
  const float* hl1g = (const float*)d_in[7];
  const float* hl1b = (const float*)d_in[8];
  const float* hW2  = (const float*)d_in[9];
  const float* hb2  = (const float*)d_in[10];
  const float* hl2g = (const float*)d_in[11];
  const float* hl2b = (const float*)d_in[12];
  const float* gW1  = (const float*)d_in[13];
  const float* gb1  = (const float*)d_in[14];
  const float* gW2  = (const float*)d_in[15];
  const float* gb2  = (const float*)d_in[16];
  const float* cW   = (const float*)d_in[17];
  const float* cb   = (const float*)d_in[18];
  const float* clng = (const float*)d_in[19];
  const float* clnb = (const float*)d_in[20];
  const float* eW1  = (const float*)d_in[21];
  const float* eb1  = (const float*)d_in[22];
  const float* eW2  = (const float*)d_in[23];
  const float* eb2  = (const float*)d_in[24];
  float* out = (float*)d_out;

  float* ws = (float*)d_ws;
  float* accg = ws;                 // B*128 floats
  float* seg  = accg + Bv * 128;    // B*4 floats

  hipMemsetAsync(accg, 0, (Bv * 128 + Bv * 4) * sizeof(float), stream);

  pe_fused<<<dim3(NBT, NJT), dim3(256), 0, stream>>>(
      x, mask, atse, fe, ae, hW1, hb1, hl1g, hl1b, hW2, hb2, hl2g, hl2b,
      gW1, gb1, gW2, gb2, accg, seg);
  pe_tail<<<dim3(Bv), dim3(64), 0, stream>>>(
      accg, seg, cW, cb, clng, clnb, eW1, eb1, eW2, eb2, out);
}